// Round 14
// baseline (141.398 us; speedup 1.0000x reference)
//
#include <hip/hip_runtime.h>
#include <hip/hip_cooperative_groups.h>

namespace cg = cooperative_groups;

typedef __attribute__((ext_vector_type(4))) float f32x4;
typedef __attribute__((ext_vector_type(8))) short bf16x8;

#define NP 4096

__device__ __forceinline__ unsigned short f2bf(float f) {
  unsigned int u = __float_as_uint(f);
  u = u + 0x7FFFu + ((u >> 16) & 1u);   // round-to-nearest-even
  return (unsigned short)(u >> 16);
}

// Single cooperative dispatch, 1024 blocks x 256 threads, all co-resident
// (4 blocks/CU; LDS 28.5 KB; launch_bounds(256,4)).
// Phase 1 (R13 pool body): block b owns peds (b%8)*512 + (b/8)*4 + {0..3}
// (XCD-contiguous slab; blocks round-robin XCDs so producer L2 = consumer L2).
// Lane owns j, loads pos/past[j] once, serves 4 peds. Per in-range pair ONE
// u64 LDS atomic packing (qx+2^14)<<38 | (qy+2^14)<<12 | 1, scale 2^-11
// (order-independent integer accumulation). Binning: fma approx + exact-IEEE-
// div fallback when any lane within 1e-4 of a cell boundary (bit-exact vs
// numpy). Self-pair lands in cell 136 with qx=qy=0, cnt 1; compensated at
// decode. Threads 0..15 convert 128 W elems fp32->bf16 (1024x128 = 256*512).
// grid.sync()  — replaces the kernel boundary (no drain/flush/ramp).
// Phase 2 (R13 gemm body): block g -> xcd=g%8, idx=g/8; m-tile =
// xcd*32+(idx&31), n-tile = idx>>5 (A-rows read from the local XCD's L2).
// 16x64 out tile, 4 waves, wave w K-slice [128w,128w+128): 4 MFMA k-steps,
// partials to red[4][64][20], one barrier, f32x4 reduce + bias + relu.
__global__ __launch_bounds__(256, 4) void fused_coop(
    const float2* __restrict__ pos, const float2* __restrict__ past,
    const float* __restrict__ W, const float* __restrict__ bias,
    unsigned short* __restrict__ Wb, unsigned short* __restrict__ gridws,
    float* __restrict__ out) {
  __shared__ unsigned long long acc[4][256];   // 8 KB
  __shared__ float red[4][64][20];             // 20.5 KB
  const int tid = threadIdx.x;
  const int b = blockIdx.x;

  // ---------------- phase 1: pool ----------------
  {
    const int ibase = (b & 7) * 512 + (b >> 3) * 4;   // XCD-contiguous slab

    if (tid < 16) {
      int idx = b * 128 + tid * 8;
      float4 w0 = *(const float4*)&W[idx];
      float4 w1 = *(const float4*)&W[idx + 4];
      bf16x8 bv;
      bv[0] = (short)f2bf(w0.x); bv[1] = (short)f2bf(w0.y);
      bv[2] = (short)f2bf(w0.z); bv[3] = (short)f2bf(w0.w);
      bv[4] = (short)f2bf(w1.x); bv[5] = (short)f2bf(w1.y);
      bv[6] = (short)f2bf(w1.z); bv[7] = (short)f2bf(w1.w);
      *(bf16x8*)&Wb[idx] = bv;
    }

    for (int idx = tid; idx < 1024; idx += 256)
      ((unsigned long long*)acc)[idx] = 0ull;
    __syncthreads();

    float2 pip[4];
    float vix[4], viy[4];
#pragma unroll
    for (int t = 0; t < 4; ++t) {
      float2 p = pos[ibase + t];
      float2 q = past[ibase + t];
      pip[t] = p;
      vix[t] = p.x - q.x;
      viy[t] = p.y - q.y;
    }
    const float inv06 = 1.0f / 0.6f;

    for (int jo = 0; jo < NP; jo += 256) {
      const int j = jo + tid;
      const float2 pj = pos[j];
      const float2 qj = past[j];
      const float vjx = pj.x - qj.x;
      const float vjy = pj.y - qj.y;
#pragma unroll
      for (int t = 0; t < 4; ++t) {
        float rx = pj.x - pip[t].x;
        float ry = pj.y - pip[t].y;
        float ax = __builtin_fmaf(rx, inv06, 8.0f);
        float ay = __builtin_fmaf(ry, inv06, 8.0f);
        bool unc = (fabsf(ax - rintf(ax)) < 1e-4f) |
                   (fabsf(ay - rintf(ay)) < 1e-4f);
        float fx, fy;
        if (__any(unc)) {
          // exact IEEE fp32 division path to match numpy floor(rel/0.6 + 8)
          fx = floorf(rx / 0.6f + 8.0f);
          fy = floorf(ry / 0.6f + 8.0f);
        } else {
          fx = floorf(ax);
          fy = floorf(ay);
        }
        int ix = (int)fx;
        int iy = (int)fy;
        if (((unsigned)ix < 16u) & ((unsigned)iy < 16u)) {
          unsigned int qx = (unsigned int)((int)rintf((vjx - vix[t]) * 2048.0f) + 16384);
          unsigned int qy = (unsigned int)((int)rintf((vjy - viy[t]) * 2048.0f) + 16384);
          unsigned long long p = ((unsigned long long)qx << 38) |
                                 ((unsigned long long)qy << 12) | 1ull;
          atomicAdd(&acc[t][(ix << 4) + iy], p);
        }
      }
    }
    __syncthreads();

    // decode u64, normalize (mean per cell), store bf16 [NP][512]
    const int cell = tid;  // 0..255
    const float selfc = (cell == 136) ? 1.0f : 0.0f;
#pragma unroll
    for (int t = 0; t < 4; ++t) {
      unsigned long long raw = acc[t][cell];
      unsigned int cnt = (unsigned int)(raw & 0xFFFull);
      int sxq = (int)((unsigned int)(raw >> 38)) - (int)(cnt << 14);
      int syq = (int)((unsigned int)((raw >> 12) & 0x3FFFFFFull)) - (int)(cnt << 14);
      float cn = (float)cnt - selfc;
      float d = fmaxf(cn, 1.0f);
      float sx = (float)sxq * (1.0f / 2048.0f);
      float sy = (float)syq * (1.0f / 2048.0f);
      unsigned int packed =
          ((unsigned int)f2bf(sy / d) << 16) | (unsigned int)f2bf(sx / d);
      *(unsigned int*)&gridws[(size_t)(ibase + t) * 512 + cell * 2] = packed;
    }
  }

  cg::this_grid().sync();

  // ---------------- phase 2: gemm ----------------
  {
    const int lane = tid & 63;
    const int w = tid >> 6;            // 0..3 K-slice
    const int xcd = b & 7;
    const int idx = b >> 3;
    const int mbase = (xcd * 32 + (idx & 31)) * 16;
    const int nbase = (idx >> 5) * 64;
    const int lrow = lane & 15;
    const int lk8 = (lane >> 4) * 8;
    const unsigned short* A = gridws;

    f32x4 gacc[4] = {};
#pragma unroll
    for (int ksp = 0; ksp < 4; ksp += 2) {
      bf16x8 a[2], bb[2][4];
#pragma unroll
      for (int u = 0; u < 2; ++u) {
        const int k0 = w * 128 + (ksp + u) * 32 + lk8;
        a[u] = *(const bf16x8*)&A[(size_t)(mbase + lrow) * 512 + k0];
#pragma unroll
        for (int nf = 0; nf < 4; ++nf)
          bb[u][nf] = *(const bf16x8*)&Wb[(size_t)(nbase + nf * 16 + lrow) * 512 + k0];
      }
#pragma unroll
      for (int u = 0; u < 2; ++u)
#pragma unroll
        for (int nf = 0; nf < 4; ++nf)
          gacc[nf] = __builtin_amdgcn_mfma_f32_16x16x32_bf16(
              a[u], bb[u][nf], gacc[nf], 0, 0, 0);
    }

    // D layout: row(m) = (lane>>4)*4 + q, col(n) = nf*16 + (lane&15)
    const int rq = (lane >> 4) * 4;
#pragma unroll
    for (int nf = 0; nf < 4; ++nf)
      *(f32x4*)&red[w][nf * 16 + lrow][rq] = gacc[nf];
    __syncthreads();

    const int col = tid & 63;
    const int mq = (tid >> 6) * 4;
    f32x4 s = {};
#pragma unroll
    for (int w2 = 0; w2 < 4; ++w2) {
      f32x4 r = *(const f32x4*)&red[w2][col][mq];
      s += r;
    }
    const float bv = bias[nbase + col];
#pragma unroll
    for (int q = 0; q < 4; ++q)
      out[(size_t)(mbase + mq + q) * 256 + nbase + col] = fmaxf(s[q] + bv, 0.0f);
  }
}

extern "C" void kernel_launch(void* const* d_in, const int* in_sizes, int n_in,
                              void* d_out, int out_size, void* d_ws, size_t ws_size,
                              hipStream_t stream) {
  // inputs: 0=h (unused), 1=positions, 2=past_positions, 3=W_emb, 4=b_emb
  const float2* pos = (const float2*)d_in[1];
  const float2* past = (const float2*)d_in[2];
  const float* W = (const float*)d_in[3];
  const float* bias = (const float*)d_in[4];
  float* out = (float*)d_out;

  unsigned short* gridws = (unsigned short*)d_ws;                         // 4 MB
  unsigned short* Wb = (unsigned short*)((char*)d_ws + 4 * 1024 * 1024);  // 256 KB

  void* args[] = {(void*)&pos, (void*)&past, (void*)&W, (void*)&bias,
                  (void*)&Wb, (void*)&gridws, (void*)&out};
  hipLaunchCooperativeKernel((const void*)fused_coop, dim3(1024), dim3(256),
                             args, 0, stream);
}

// Round 15
// 38.916 us; speedup vs baseline: 3.6334x; 3.6334x over previous
//
#include <hip/hip_runtime.h>

typedef __attribute__((ext_vector_type(4))) float f32x4;
typedef __attribute__((ext_vector_type(8))) short bf16x8;

#define NP 4096
#define PB 8

__device__ __forceinline__ unsigned short f2bf(float f) {
  unsigned int u = __float_as_uint(f);
  u = u + 0x7FFFu + ((u >> 16) & 1u);   // round-to-nearest-even
  return (unsigned short)(u >> 16);
}

// ---------------- W fp32 -> bf16 (separate kernel: Wb lines are CLEAN
// (written-back small kernel) before the gemm broadcasts-reads them; inline
// conversion in pool left them dirty-scattered across all 8 XCD L2s) --------
__global__ __launch_bounds__(256) void wconv_kernel(
    const float* __restrict__ W, unsigned short* __restrict__ Wb) {
  int i = (blockIdx.x * 256 + threadIdx.x) * 8;
  float4 w0 = *(const float4*)&W[i];
  float4 w1 = *(const float4*)&W[i + 4];
  bf16x8 bv;
  bv[0] = (short)f2bf(w0.x); bv[1] = (short)f2bf(w0.y);
  bv[2] = (short)f2bf(w0.z); bv[3] = (short)f2bf(w0.w);
  bv[4] = (short)f2bf(w1.x); bv[5] = (short)f2bf(w1.y);
  bv[6] = (short)f2bf(w1.z); bv[7] = (short)f2bf(w1.w);
  *(bf16x8*)&Wb[i] = bv;
}

// ---------------- pool: lane-owns-j, 8 peds amortized, full occupancy ------
// 512 blocks x 512 threads, launch_bounds(512,4): 4 blocks/CU, 32 waves/CU
// (R12 ran this shape at 30% occupancy -- confounded; this isolates it).
// Block b owns peds (b&7)*512 + (b>>3)*8 + {0..7} (XCD-contiguous slab so the
// XCD-matched gemm reads gridws from its local L2, per R13).
// Lane owns j: pos/past[j] loaded ONCE, serves 8 peds (halved loads, velocity
// computed once). Per in-range pair ONE u64 LDS atomic packing
// (qx+2^14)<<38 | (qy+2^14)<<12 | 1, scale 2^-11 (order-independent).
// Binning: fma approx + exact-IEEE-div fallback when any lane within 1e-4 of
// a cell boundary (bit-exact vs numpy). Self-pair lands in cell 136 with
// qx=qy=0, cnt 1; compensated at decode.
__global__ __launch_bounds__(512, 4) void pool_kernel(
    const float2* __restrict__ pos, const float2* __restrict__ past,
    unsigned short* __restrict__ gridws) {
  __shared__ unsigned long long acc[PB][256];   // 16 KB
  const int tid = threadIdx.x;
  const int b = blockIdx.x;
  const int ibase = (b & 7) * 512 + (b >> 3) * PB;   // XCD-contiguous slab

  for (int idx = tid; idx < PB * 256; idx += 512)
    ((unsigned long long*)acc)[idx] = 0ull;
  __syncthreads();

  float pxv[PB], pyv[PB], vix[PB], viy[PB];
#pragma unroll
  for (int t = 0; t < PB; ++t) {
    float2 p = pos[ibase + t];
    float2 q = past[ibase + t];
    pxv[t] = p.x;
    pyv[t] = p.y;
    vix[t] = p.x - q.x;
    viy[t] = p.y - q.y;
  }
  const float inv06 = 1.0f / 0.6f;

  for (int jo = 0; jo < NP; jo += 512) {
    const int j = jo + tid;
    const float2 pj = pos[j];
    const float2 qj = past[j];
    const float vjx = pj.x - qj.x;
    const float vjy = pj.y - qj.y;
#pragma unroll
    for (int t = 0; t < PB; ++t) {
      float rx = pj.x - pxv[t];
      float ry = pj.y - pyv[t];
      float ax = __builtin_fmaf(rx, inv06, 8.0f);
      float ay = __builtin_fmaf(ry, inv06, 8.0f);
      bool unc = (fabsf(ax - rintf(ax)) < 1e-4f) |
                 (fabsf(ay - rintf(ay)) < 1e-4f);
      float fx, fy;
      if (__any(unc)) {
        // exact IEEE fp32 division path to match numpy floor(rel/0.6 + 8)
        fx = floorf(rx / 0.6f + 8.0f);
        fy = floorf(ry / 0.6f + 8.0f);
      } else {
        fx = floorf(ax);
        fy = floorf(ay);
      }
      int ix = (int)fx;
      int iy = (int)fy;
      if (((unsigned)ix < 16u) & ((unsigned)iy < 16u)) {
        unsigned int qx = (unsigned int)((int)rintf((vjx - vix[t]) * 2048.0f) + 16384);
        unsigned int qy = (unsigned int)((int)rintf((vjy - viy[t]) * 2048.0f) + 16384);
        unsigned long long p = ((unsigned long long)qx << 38) |
                               ((unsigned long long)qy << 12) | 1ull;
        atomicAdd(&acc[t][(ix << 4) + iy], p);
      }
    }
  }
  __syncthreads();

  // epilogue: decode u64, normalize (mean per cell), store bf16 [NP][512]
  const int cell = tid & 255;
  const int tg = (tid >> 8) * 4;     // ped group {0..3} or {4..7}
  const float selfc = (cell == 136) ? 1.0f : 0.0f;
#pragma unroll
  for (int tt = 0; tt < 4; ++tt) {
    const int t = tg + tt;
    unsigned long long raw = acc[t][cell];
    unsigned int cnt = (unsigned int)(raw & 0xFFFull);
    int sxq = (int)((unsigned int)(raw >> 38)) - (int)(cnt << 14);
    int syq = (int)((unsigned int)((raw >> 12) & 0x3FFFFFFull)) - (int)(cnt << 14);
    float cn = (float)cnt - selfc;
    float d = fmaxf(cn, 1.0f);
    float sx = (float)sxq * (1.0f / 2048.0f);
    float sy = (float)syq * (1.0f / 2048.0f);
    unsigned int packed =
        ((unsigned int)f2bf(sy / d) << 16) | (unsigned int)f2bf(sx / d);
    *(unsigned int*)&gridws[(size_t)(ibase + t) * 512 + cell * 2] = packed;
  }
}

// ---------------- GEMM: split-K, XCD-matched consumer (R13 body) -----------
// C[4096][256] = relu(A[4096][512](bf16) @ Wb[256][512]^T + b), fp32 out.
// 1-D grid, 1024 blocks: block g -> xcd=g%8, idx=g/8; m-tile = xcd*32+(idx&31)
// (peds xcd*512+...), n-tile = idx>>5. A-rows read from the local XCD's L2;
// Wb broadcast-read but CLEAN (separate wconv kernel). Block = 16x64 out
// tile, 4 waves; wave w owns K-slice [128w,128w+128): 4 MFMA k-steps, 2-deep
// loads, no k-barriers. Partials red[4][64][20], one barrier, f32x4 reduce +
// bias + relu + coalesced stores.
__global__ __launch_bounds__(256) void gemm_kernel(
    const unsigned short* __restrict__ A, const unsigned short* __restrict__ Wb,
    const float* __restrict__ bias, float* __restrict__ out) {
  __shared__ float red[4][64][20];
  const int tid = threadIdx.x;
  const int lane = tid & 63;
  const int w = tid >> 6;            // 0..3 K-slice
  const int g = blockIdx.x;
  const int xcd = g & 7;
  const int idx = g >> 3;
  const int mbase = (xcd * 32 + (idx & 31)) * 16;
  const int nbase = (idx >> 5) * 64;
  const int lrow = lane & 15;
  const int lk8 = (lane >> 4) * 8;

  f32x4 acc[4] = {};
#pragma unroll
  for (int ksp = 0; ksp < 4; ksp += 2) {
    bf16x8 a[2], b[2][4];
#pragma unroll
    for (int u = 0; u < 2; ++u) {
      const int k0 = w * 128 + (ksp + u) * 32 + lk8;
      a[u] = *(const bf16x8*)&A[(size_t)(mbase + lrow) * 512 + k0];
#pragma unroll
      for (int nf = 0; nf < 4; ++nf)
        b[u][nf] = *(const bf16x8*)&Wb[(size_t)(nbase + nf * 16 + lrow) * 512 + k0];
    }
#pragma unroll
    for (int u = 0; u < 2; ++u)
#pragma unroll
      for (int nf = 0; nf < 4; ++nf)
        acc[nf] = __builtin_amdgcn_mfma_f32_16x16x32_bf16(
            a[u], b[u][nf], acc[nf], 0, 0, 0);
  }

  // D layout: row(m) = (lane>>4)*4 + q, col(n) = nf*16 + (lane&15)
  const int rq = (lane >> 4) * 4;
#pragma unroll
  for (int nf = 0; nf < 4; ++nf)
    *(f32x4*)&red[w][nf * 16 + lrow][rq] = acc[nf];
  __syncthreads();

  const int col = tid & 63;
  const int mq = (tid >> 6) * 4;
  f32x4 s = {};
#pragma unroll
  for (int w2 = 0; w2 < 4; ++w2) {
    f32x4 r = *(const f32x4*)&red[w2][col][mq];
    s += r;
  }
  const float bv = bias[nbase + col];
#pragma unroll
  for (int q = 0; q < 4; ++q)
    out[(size_t)(mbase + mq + q) * 256 + nbase + col] = fmaxf(s[q] + bv, 0.0f);
}

extern "C" void kernel_launch(void* const* d_in, const int* in_sizes, int n_in,
                              void* d_out, int out_size, void* d_ws, size_t ws_size,
                              hipStream_t stream) {
  // inputs: 0=h (unused), 1=positions, 2=past_positions, 3=W_emb, 4=b_emb
  const float2* pos = (const float2*)d_in[1];
  const float2* past = (const float2*)d_in[2];
  const float* W = (const float*)d_in[3];
  const float* bias = (const float*)d_in[4];
  float* out = (float*)d_out;

  unsigned short* gridws = (unsigned short*)d_ws;                         // 4 MB
  unsigned short* Wb = (unsigned short*)((char*)d_ws + 4 * 1024 * 1024);  // 256 KB

  wconv_kernel<<<(256 * 512) / (256 * 8), 256, 0, stream>>>(W, Wb);
  pool_kernel<<<NP / PB, 512, 0, stream>>>(pos, past, gridws);
  gemm_kernel<<<1024, 256, 0, stream>>>(gridws, Wb, bias, out);
}

// Round 16
// 36.342 us; speedup vs baseline: 3.8907x; 1.0708x over previous
//
#include <hip/hip_runtime.h>

typedef __attribute__((ext_vector_type(4))) float f32x4;
typedef __attribute__((ext_vector_type(8))) short bf16x8;

#define NP 4096

__device__ __forceinline__ unsigned short f2bf(float f) {
  unsigned int u = __float_as_uint(f);
  u = u + 0x7FFFu + ((u >> 16) & 1u);   // round-to-nearest-even
  return (unsigned short)(u >> 16);
}

// ---------------- pool: R13 body, byte-identical (best measured) -----------
// Block b owns peds (b&7)*512 + (b>>3)*4 + {0..3} (XCD-contiguous slab;
// blocks round-robin XCDs so producer L2 = consumer L2). Lane owns j,
// loads pos/past[j] ONCE, serves 4 peds. Per in-range pair ONE u64 LDS atomic
// packing (qx+2^14)<<38 | (qy+2^14)<<12 | 1, scale 2^-11 (order-independent
// integer accumulation). Binning: fma approx + exact-IEEE-div fallback when
// any lane within 1e-4 of a cell boundary (bit-exact vs numpy). Self-pair
// lands in cell 136 with qx=qy=0, cnt 1; compensated at decode.
// Threads 0..15 convert 128 W elems fp32->bf16 (1024 x 128 = 256*512).
__global__ __launch_bounds__(256, 8) void pool_kernel(
    const float2* __restrict__ pos, const float2* __restrict__ past,
    const float* __restrict__ W, unsigned short* __restrict__ Wb,
    unsigned short* __restrict__ gridws) {
  __shared__ unsigned long long acc[4][256];   // 8 KB
  const int tid = threadIdx.x;
  const int b = blockIdx.x;
  const int ibase = (b & 7) * 512 + (b >> 3) * 4;   // XCD-contiguous ped slab

  if (tid < 16) {
    int idx = b * 128 + tid * 8;
    float4 w0 = *(const float4*)&W[idx];
    float4 w1 = *(const float4*)&W[idx + 4];
    bf16x8 bv;
    bv[0] = (short)f2bf(w0.x); bv[1] = (short)f2bf(w0.y);
    bv[2] = (short)f2bf(w0.z); bv[3] = (short)f2bf(w0.w);
    bv[4] = (short)f2bf(w1.x); bv[5] = (short)f2bf(w1.y);
    bv[6] = (short)f2bf(w1.z); bv[7] = (short)f2bf(w1.w);
    *(bf16x8*)&Wb[idx] = bv;
  }

  for (int idx = tid; idx < 1024; idx += 256)
    ((unsigned long long*)acc)[idx] = 0ull;
  __syncthreads();

  float2 pip[4];
  float vix[4], viy[4];
#pragma unroll
  for (int t = 0; t < 4; ++t) {
    float2 p = pos[ibase + t];
    float2 q = past[ibase + t];
    pip[t] = p;
    vix[t] = p.x - q.x;
    viy[t] = p.y - q.y;
  }
  const float inv06 = 1.0f / 0.6f;

  for (int jo = 0; jo < NP; jo += 256) {
    const int j = jo + tid;
    const float2 pj = pos[j];
    const float2 qj = past[j];
    const float vjx = pj.x - qj.x;
    const float vjy = pj.y - qj.y;
#pragma unroll
    for (int t = 0; t < 4; ++t) {
      float rx = pj.x - pip[t].x;
      float ry = pj.y - pip[t].y;
      float ax = __builtin_fmaf(rx, inv06, 8.0f);
      float ay = __builtin_fmaf(ry, inv06, 8.0f);
      bool unc = (fabsf(ax - rintf(ax)) < 1e-4f) |
                 (fabsf(ay - rintf(ay)) < 1e-4f);
      float fx, fy;
      if (__any(unc)) {
        // exact IEEE fp32 division path to match numpy floor(rel/0.6 + 8)
        fx = floorf(rx / 0.6f + 8.0f);
        fy = floorf(ry / 0.6f + 8.0f);
      } else {
        fx = floorf(ax);
        fy = floorf(ay);
      }
      int ix = (int)fx;
      int iy = (int)fy;
      if (((unsigned)ix < 16u) & ((unsigned)iy < 16u)) {
        unsigned int qx = (unsigned int)((int)rintf((vjx - vix[t]) * 2048.0f) + 16384);
        unsigned int qy = (unsigned int)((int)rintf((vjy - viy[t]) * 2048.0f) + 16384);
        unsigned long long p = ((unsigned long long)qx << 38) |
                               ((unsigned long long)qy << 12) | 1ull;
        atomicAdd(&acc[t][(ix << 4) + iy], p);
      }
    }
  }
  __syncthreads();

  // epilogue: decode u64, normalize (mean per cell), store bf16 [NP][512]
  const int cell = tid;  // 0..255
  const float selfc = (cell == 136) ? 1.0f : 0.0f;
#pragma unroll
  for (int t = 0; t < 4; ++t) {
    unsigned long long raw = acc[t][cell];
    unsigned int cnt = (unsigned int)(raw & 0xFFFull);
    int sxq = (int)((unsigned int)(raw >> 38)) - (int)(cnt << 14);
    int syq = (int)((unsigned int)((raw >> 12) & 0x3FFFFFFull)) - (int)(cnt << 14);
    float cn = (float)cnt - selfc;
    float d = fmaxf(cn, 1.0f);
    float sx = (float)sxq * (1.0f / 2048.0f);
    float sy = (float)syq * (1.0f / 2048.0f);
    unsigned int packed =
        ((unsigned int)f2bf(sy / d) << 16) | (unsigned int)f2bf(sx / d);
    *(unsigned int*)&gridws[(size_t)(ibase + t) * 512 + cell * 2] = packed;
  }
}

// ---------------- GEMM: fine-grain split-K, 32 waves/CU --------------------
// C[4096][256] = relu(A[4096][512](bf16) @ Wb[256][512]^T + b), fp32 out.
// BM=16, BN=32, 4-way split-K: 2048 blocks x 256 thr = 8 blocks/CU (LDS
// 10.2 KB, launch_bounds(256,8)) = 32 waves/CU -- full TLP to hide L2
// latency, the term every previous (<=16 waves/CU) gemm left exposed.
// Wave w owns K-slice [128w,128w+128): 12 independent 16B loads, 8 MFMAs.
// XCD-matched: block g -> xcd=g&7, idx=g>>3; m-tile=xcd*32+(idx&31) (reads
// A-rows from the local XCD's L2, per R13), n-tile=idx>>5.
// Partials red[4][32][20]; one barrier; 2 outputs/thread + bias + relu.
__global__ __launch_bounds__(256, 8) void gemm_kernel(
    const unsigned short* __restrict__ A, const unsigned short* __restrict__ Wb,
    const float* __restrict__ bias, float* __restrict__ out) {
  __shared__ float red[4][32][20];
  const int tid = threadIdx.x;
  const int lane = tid & 63;
  const int w = tid >> 6;            // 0..3 K-slice
  const int g = blockIdx.x;
  const int xcd = g & 7;
  const int idx = g >> 3;
  const int mbase = (xcd * 32 + (idx & 31)) * 16;
  const int nbase = (idx >> 5) * 32;
  const int lrow = lane & 15;
  const int lk8 = (lane >> 4) * 8;

  f32x4 acc[2] = {};
#pragma unroll
  for (int ksp = 0; ksp < 4; ksp += 2) {
    bf16x8 a[2], b[2][2];
#pragma unroll
    for (int u = 0; u < 2; ++u) {
      const int k0 = w * 128 + (ksp + u) * 32 + lk8;
      a[u] = *(const bf16x8*)&A[(size_t)(mbase + lrow) * 512 + k0];
      b[u][0] = *(const bf16x8*)&Wb[(size_t)(nbase + lrow) * 512 + k0];
      b[u][1] = *(const bf16x8*)&Wb[(size_t)(nbase + 16 + lrow) * 512 + k0];
    }
#pragma unroll
    for (int u = 0; u < 2; ++u) {
      acc[0] = __builtin_amdgcn_mfma_f32_16x16x32_bf16(a[u], b[u][0], acc[0], 0, 0, 0);
      acc[1] = __builtin_amdgcn_mfma_f32_16x16x32_bf16(a[u], b[u][1], acc[1], 0, 0, 0);
    }
  }

  // D layout: row(m) = (lane>>4)*4 + q, col(n) = nf*16 + (lane&15)
  const int rq = (lane >> 4) * 4;
#pragma unroll
  for (int nf = 0; nf < 2; ++nf)
    *(f32x4*)&red[w][nf * 16 + lrow][rq] = acc[nf];
  __syncthreads();

  // reduce: thread -> (col = tid&31, m pair = (tid>>5)*2)
  const int col = tid & 31;
  const int m0 = (tid >> 5) * 2;
  float s0 = 0.f, s1 = 0.f;
#pragma unroll
  for (int w2 = 0; w2 < 4; ++w2) {
    s0 += red[w2][col][m0];
    s1 += red[w2][col][m0 + 1];
  }
  const float bv = bias[nbase + col];
  out[(size_t)(mbase + m0) * 256 + nbase + col] = fmaxf(s0 + bv, 0.0f);
  out[(size_t)(mbase + m0 + 1) * 256 + nbase + col] = fmaxf(s1 + bv, 0.0f);
}

extern "C" void kernel_launch(void* const* d_in, const int* in_sizes, int n_in,
                              void* d_out, int out_size, void* d_ws, size_t ws_size,
                              hipStream_t stream) {
  // inputs: 0=h (unused), 1=positions, 2=past_positions, 3=W_emb, 4=b_emb
  const float2* pos = (const float2*)d_in[1];
  const float2* past = (const float2*)d_in[2];
  const float* W = (const float*)d_in[3];
  const float* bias = (const float*)d_in[4];
  float* out = (float*)d_out;

  unsigned short* gridws = (unsigned short*)d_ws;                         // 4 MB
  unsigned short* Wb = (unsigned short*)((char*)d_ws + 4 * 1024 * 1024);  // 256 KB

  pool_kernel<<<NP / 4, 256, 0, stream>>>(pos, past, W, Wb, gridws);
  gemm_kernel<<<2048, 256, 0, stream>>>(gridws, Wb, bias, out);
}